// Round 5
// baseline (4788.971 us; speedup 1.0000x reference)
//
#include <hip/hip_runtime.h>
#include <hip/hip_bf16.h>
#include <math.h>

#define N_NODES   100000
#define N_CH      9
#define N_EDG     500000
#define NEG_SLOPE 0.2f
#define NSLOT     10           // structure slots (batch2 = 10 graphs)
#define PACK_STRIDE 500016     // u32 per graph slot (+pad)

// bucket sort geometry
#define CHUNK  8192            // edges per block in histA/scatterA
#define NBLK   62              // ceil(500000/8192)
#define NBUCK  782             // buckets of 128 nodes: dst>>7
#define BNODES 128
#define MLEN   (NBUCK * NBLK)  // 48484 matrix entries per graph
#define NBA1   190             // ceil(MLEN/256) scan blocks

// ---------------- utility ----------------

__device__ __forceinline__ float bf2f(unsigned short h) {
  return __uint_as_float(((unsigned)h) << 16);
}
// bf16 pair unpack straight from a u32 (lo = elem 2k, hi = elem 2k+1)
__device__ __forceinline__ float bflo(unsigned u) { return __uint_as_float(u << 16); }
__device__ __forceinline__ float bfhi(unsigned u) { return __uint_as_float(u & 0xffff0000u); }
__device__ __forceinline__ unsigned short f2bf(float f) {
  unsigned u = __float_as_uint(f);
  u += 0x7FFFu + ((u >> 16) & 1u);
  return (unsigned short)(u >> 16);
}
__device__ __forceinline__ float lrelu(float x) { return x > 0.f ? x : NEG_SLOPE * x; }
__device__ __forceinline__ int clampi(int x) {
  return x < 0 ? 0 : (x >= N_NODES ? N_NODES - 1 : x);
}

// ---------------- diagnostic: fill output with a constant (f32) ------------
__global__ __launch_bounds__(256) void write_const(float* __restrict__ out, float val) {
  int idx = blockIdx.x * 256 + threadIdx.x;
  out[idx] = val;
}

// ---------------- GEMM + fused attention dots ------------------------------
// H[M,64](bf16) = A[M,64] @ W[64,64](f32); also sS = H.a_src, sD = H.a_dst
// computed from the f32 accumulators (register-resident) via padded-LDS
// reduction.  256 thr, 128 rows/block, 8x4 thread tile.
#define GEMM_BODY(LOAD_A)                                                     \
  __shared__ float Ws[64 * 64];                                               \
  __shared__ float Xs[64 * 132];                                              \
  __shared__ float redS[128 * 17];   /* [row][cg] stride 17: 2-way conflicts */\
  __shared__ float redD[128 * 17];                                            \
  const int tx = threadIdx.x;                                                 \
  const int r0 = blockIdx.x * 128;                                            \
  _Pragma("unroll")                                                           \
  for (int i = 0; i < 16; ++i) Ws[tx + 256 * i] = W[tx + 256 * i];            \
  _Pragma("unroll")                                                           \
  for (int it = 0; it < 8; ++it) {                                            \
    int f = tx + 256 * it;                                                    \
    int r = f >> 4;                                                           \
    int k0 = (f & 15) << 2;                                                   \
    float4 v = make_float4(0.f, 0.f, 0.f, 0.f);                               \
    if (r0 + r < M) { LOAD_A }                                                \
    Xs[(k0 + 0) * 132 + r] = v.x;                                             \
    Xs[(k0 + 1) * 132 + r] = v.y;                                             \
    Xs[(k0 + 2) * 132 + r] = v.z;                                             \
    Xs[(k0 + 3) * 132 + r] = v.w;                                             \
  }                                                                           \
  __syncthreads();                                                            \
  const int cg = tx & 15, rg = tx >> 4;                                       \
  float acc[8][4];                                                            \
  _Pragma("unroll")                                                           \
  for (int i = 0; i < 8; ++i)                                                 \
    _Pragma("unroll")                                                         \
    for (int j = 0; j < 4; ++j) acc[i][j] = 0.f;                              \
  _Pragma("unroll 4")                                                         \
  for (int k = 0; k < 64; ++k) {                                              \
    float4 w4 = *(const float4*)(Ws + k * 64 + cg * 4);                       \
    float4 x0 = *(const float4*)(Xs + k * 132 + rg * 8);                      \
    float4 x1 = *(const float4*)(Xs + k * 132 + rg * 8 + 4);                  \
    float xr[8] = {x0.x, x0.y, x0.z, x0.w, x1.x, x1.y, x1.z, x1.w};           \
    float wr[4] = {w4.x, w4.y, w4.z, w4.w};                                   \
    _Pragma("unroll")                                                         \
    for (int i = 0; i < 8; ++i)                                               \
      _Pragma("unroll")                                                       \
      for (int j = 0; j < 4; ++j) acc[i][j] += xr[i] * wr[j];                 \
  }                                                                           \
  float4 s4 = *(const float4*)(a_src + cg * 4);                               \
  float4 d4 = *(const float4*)(a_dst + cg * 4);                               \
  _Pragma("unroll")                                                           \
  for (int i = 0; i < 8; ++i) {                                               \
    int row = rg * 8 + i;                                                     \
    redS[row * 17 + cg] =                                                     \
        acc[i][0] * s4.x + acc[i][1] * s4.y + acc[i][2] * s4.z + acc[i][3] * s4.w; \
    redD[row * 17 + cg] =                                                     \
        acc[i][0] * d4.x + acc[i][1] * d4.y + acc[i][2] * d4.z + acc[i][3] * d4.w; \
    int r = r0 + row;                                                         \
    if (r < M) {                                                              \
      ushort4 o;                                                              \
      o.x = f2bf(acc[i][0]); o.y = f2bf(acc[i][1]);                           \
      o.z = f2bf(acc[i][2]); o.w = f2bf(acc[i][3]);                           \
      *(ushort4*)(Hout + (size_t)r * 64 + cg * 4) = o;                        \
    }                                                                         \
  }                                                                           \
  __syncthreads();                                                            \
  if (tx < 128) {                                                             \
    float s = 0.f;                                                            \
    _Pragma("unroll")                                                         \
    for (int c2 = 0; c2 < 16; ++c2) s += redS[tx * 17 + c2];                  \
    if (r0 + tx < M) sS[r0 + tx] = s;                                         \
  } else {                                                                    \
    int row = tx - 128;                                                       \
    float s = 0.f;                                                            \
    _Pragma("unroll")                                                         \
    for (int c2 = 0; c2 < 16; ++c2) s += redD[row * 17 + c2];                 \
    if (r0 + row < M) sD[r0 + row] = s;                                       \
  }

__global__ __launch_bounds__(256) void gemm64_f32(const float* __restrict__ A,
                                                  const float* __restrict__ W,
                                                  const float* __restrict__ a_src,
                                                  const float* __restrict__ a_dst,
                                                  unsigned short* __restrict__ Hout,
                                                  float* __restrict__ sS,
                                                  float* __restrict__ sD, int M) {
  GEMM_BODY(v = *(const float4*)(A + (size_t)(r0 + r) * 64 + k0);)
}

__global__ __launch_bounds__(256) void gemm64_bf(const unsigned short* __restrict__ A,
                                                 const float* __restrict__ W,
                                                 const float* __restrict__ a_src,
                                                 const float* __restrict__ a_dst,
                                                 unsigned short* __restrict__ Hout,
                                                 float* __restrict__ sS,
                                                 float* __restrict__ sD, int M) {
  GEMM_BODY(ushort4 h = *(const ushort4*)(A + (size_t)(r0 + r) * 64 + k0);
            v.x = bf2f(h.x); v.y = bf2f(h.y); v.z = bf2f(h.z); v.w = bf2f(h.w);)
}

// ---------------- batched CSR-bucket build (structure only, input-static) --
// Graph gi = c*2+layer.  Batch1: graphs 0..7 before the loop; batch2: graphs
// 8..17 before channel 4.  No global atomics anywhere.  Buckets are 128
// nodes (b = dst>>7); within-bucket order is irrelevant (aggB uses LDS
// accumulators), so there is NO second-level sort.
//   histA:    per-block LDS histogram over 782 buckets -> histM[g][b*NBLK+blk]
//   scanA*:   exclusive scan of the 48484-entry matrix per graph (in place)
//   scatterA: block-local counting sort by bucket in LDS, then SEQUENTIAL
//             write-out so each (bucket,block) run (~10.5 edges) leaves as
//             consecutive lanes of one wave -> near-full-line stores.

__global__ __launch_bounds__(256) void histA(const int* __restrict__ EI, int base,
                                             int* __restrict__ histM) {
  const int g = blockIdx.y;
  const int* dst = EI + ((size_t)(base + g) * 2 + 1) * N_EDG;
  __shared__ int h[NBUCK];
  for (int i = threadIdx.x; i < NBUCK; i += 256) h[i] = 0;
  __syncthreads();
  const int e0 = blockIdx.x * CHUNK;
  for (int k = 0; k < CHUNK; k += 256) {
    int i = e0 + k + threadIdx.x;
    if (i < N_EDG) atomicAdd(&h[clampi(dst[i]) >> 7], 1);
  }
  __syncthreads();
  for (int i = threadIdx.x; i < NBUCK; i += 256)
    histM[(size_t)g * MLEN + i * NBLK + blockIdx.x] = h[i];
}

__global__ __launch_bounds__(256) void scanA1(int* __restrict__ data,
                                              int* __restrict__ bsum) {
  const int g = blockIdx.y;
  __shared__ int sh[256];
  int i = blockIdx.x * 256 + threadIdx.x;
  int x = (i < MLEN) ? data[(size_t)g * MLEN + i] : 0;
  sh[threadIdx.x] = x;
  __syncthreads();
  for (int off = 1; off < 256; off <<= 1) {
    int t = (threadIdx.x >= off) ? sh[threadIdx.x - off] : 0;
    __syncthreads();
    sh[threadIdx.x] += t;
    __syncthreads();
  }
  if (i < MLEN) data[(size_t)g * MLEN + i] = sh[threadIdx.x] - x;  // exclusive
  if (threadIdx.x == 255) bsum[g * 512 + blockIdx.x] = sh[255];
}

__global__ __launch_bounds__(512) void scanA2(int* __restrict__ bsum) {
  const int g = blockIdx.x;
  __shared__ int sh[512];
  int x = (threadIdx.x < NBA1) ? bsum[g * 512 + threadIdx.x] : 0;
  sh[threadIdx.x] = x;
  __syncthreads();
  for (int off = 1; off < 512; off <<= 1) {
    int t = (threadIdx.x >= off) ? sh[threadIdx.x - off] : 0;
    __syncthreads();
    sh[threadIdx.x] += t;
    __syncthreads();
  }
  if (threadIdx.x < NBA1) bsum[g * 512 + threadIdx.x] = sh[threadIdx.x] - x;  // exclusive
}

__global__ void scanA3(int* __restrict__ data, const int* __restrict__ bsum) {
  const int g = blockIdx.y;
  int i = blockIdx.x * 256 + threadIdx.x;
  if (i < MLEN) data[(size_t)g * MLEN + i] += bsum[g * 512 + blockIdx.x];
}

// block-local counting sort by coarse bucket + coalesced sequential writeout.
__global__ __launch_bounds__(256) void scatterA(const int* __restrict__ EI, int base,
                                                const int* __restrict__ histM,
                                                unsigned* __restrict__ pack) {
  const int g = blockIdx.y;
  const int* srcp = EI + ((size_t)(base + g) * 2 + 0) * N_EDG;
  const int* dstp = EI + ((size_t)(base + g) * 2 + 1) * N_EDG;
  __shared__ unsigned ed[CHUNK];          // 32 KB: bucket-grouped entries
  __shared__ unsigned short bkt[CHUNK];   // 16 KB: bucket id per slot
  __shared__ int lcnt[NBUCK];
  __shared__ int ebase[NBUCK];
  __shared__ int gbase[NBUCK];
  __shared__ int sc[1024];
  const int t = threadIdx.x;
  const int e0 = blockIdx.x * CHUNK;
  const int nE = (N_EDG - e0 < CHUNK) ? (N_EDG - e0) : CHUNK;

  for (int i = t; i < NBUCK; i += 256) {
    lcnt[i] = 0;
    gbase[i] = histM[(size_t)g * MLEN + i * NBLK + blockIdx.x];
  }
  __syncthreads();
  // pass 1: local histogram (reads dst; stays hot in L1/L2 for pass 2)
  for (int k = t; k < nE; k += 256)
    atomicAdd(&lcnt[clampi(dstp[e0 + k]) >> 7], 1);
  __syncthreads();
  // block-wide inclusive scan of 1024-padded lcnt (each thread owns 4 slots)
  int v[4];
#pragma unroll
  for (int qq = 0; qq < 4; ++qq) {
    int ii = t + 256 * qq;
    v[qq] = (ii < NBUCK) ? lcnt[ii] : 0;
    sc[ii] = v[qq];
  }
  __syncthreads();
  for (int off = 1; off < 1024; off <<= 1) {
    int a[4];
#pragma unroll
    for (int qq = 0; qq < 4; ++qq) {
      int ii = t + 256 * qq;
      a[qq] = (ii >= off) ? sc[ii - off] : 0;
    }
    __syncthreads();
#pragma unroll
    for (int qq = 0; qq < 4; ++qq) sc[t + 256 * qq] += a[qq];
    __syncthreads();
  }
#pragma unroll
  for (int qq = 0; qq < 4; ++qq) {
    int ii = t + 256 * qq;
    if (ii < NBUCK) { ebase[ii] = sc[ii] - v[qq]; lcnt[ii] = 0; }
  }
  __syncthreads();
  // pass 2: scatter into LDS, bucket-grouped (rank via LDS atomics)
  for (int k = t; k < nE; k += 256) {
    int d = clampi(dstp[e0 + k]);
    int s = clampi(srcp[e0 + k]);
    int b = d >> 7;
    int slot = ebase[b] + atomicAdd(&lcnt[b], 1);
    ed[slot] = ((unsigned)s << 7) | (unsigned)(d & 127);
    bkt[slot] = (unsigned short)b;
  }
  __syncthreads();
  // pass 3: sequential write-out -> bucket-runs leave as consecutive lanes
  unsigned* pk = pack + (size_t)g * PACK_STRIDE;
  for (int i = t; i < nE; i += 256) {
    int b = bkt[i];
    pk[gbase[b] + (i - ebase[b])] = ed[i];
  }
}

// ---------------- bucket-parallel GAT aggregation --------------------------
// One block per 128-node bucket.  Edges are consumed fully in parallel (no
// per-node latency chains): lane-octet (e8=lane>>3, g8=lane&7) gathers one
// edge's H row (uint4 = feats 8*g8..) and atomically accumulates w*H into a
// 128x65-padded f32 LDS accumulator (pad -> bank=(node+feat)&31, spread).
// Epilogue: self-loop (coalesced H read of own nodes), divide, bias, then
// mode 0: X1=bf16(relu(v));  mode 1: online channel combine (O,Mn,Sn) with
// coalesced float4 RMW; last channel divides into out.
__global__ __launch_bounds__(256) void aggB(const unsigned short* __restrict__ H,
                                            const float* __restrict__ sS,
                                            const float* __restrict__ sD,
                                            const int* __restrict__ histM,  // slot base
                                            const unsigned* __restrict__ pack,
                                            const float* __restrict__ bias,
                                            unsigned short* __restrict__ X1out,
                                            const float* __restrict__ att_c,
                                            float* __restrict__ O,
                                            float* __restrict__ Mn,
                                            float* __restrict__ Sn,
                                            float* __restrict__ outF,
                                            int mode, int first, int last) {
  __shared__ float acc_s[BNODES * 65];   // 33.3 KB, +65 pad
  __shared__ float den_s[BNODES];
  const int b = blockIdx.x;
  const int n0 = b * BNODES;
  const int nc = (N_NODES - n0 < BNODES) ? (N_NODES - n0) : BNODES;
  const int beg = histM[b * NBLK];
  const int end = (b + 1 < NBUCK) ? histM[(b + 1) * NBLK] : N_EDG;
  const int tx = threadIdx.x;
  const int wid = tx >> 6;
  const int lane = tx & 63;

  for (int i = tx; i < BNODES * 65; i += 256) acc_s[i] = 0.f;
  if (tx < BNODES) den_s[tx] = 0.f;
  __syncthreads();

  // ---- edge phase: 16 edges per wave-iter (2 per lane-octet, ILP) ----
  const int e8 = lane >> 3, g8 = lane & 7;
  for (int base = beg + wid * 16; base < end; base += 64) {
    int i0 = base + e8;
    int i1 = base + 8 + e8;
#pragma unroll
    for (int u = 0; u < 2; ++u) {
      int idx = u ? i1 : i0;
      if (idx < end) {
        unsigned p = pack[idx];
        int s = (int)(p >> 7);
        int dl = (int)(p & 127u);
        float w = __expf(lrelu(sS[s] + sD[n0 + dl]));
        uint4 hv = *(const uint4*)(H + ((size_t)s << 6) + (g8 << 3));
        float* ap = acc_s + dl * 65 + g8 * 8;
        atomicAdd(ap + 0, w * bflo(hv.x));
        atomicAdd(ap + 1, w * bfhi(hv.x));
        atomicAdd(ap + 2, w * bflo(hv.y));
        atomicAdd(ap + 3, w * bfhi(hv.y));
        atomicAdd(ap + 4, w * bflo(hv.z));
        atomicAdd(ap + 5, w * bfhi(hv.z));
        atomicAdd(ap + 6, w * bflo(hv.w));
        atomicAdd(ap + 7, w * bfhi(hv.w));
        if (g8 == 0) atomicAdd(&den_s[dl], w);
      }
    }
  }
  __syncthreads();

  // ---- epilogue: 16 lanes per node (q = feature quad), 8 passes ----
  const int sub = lane >> 4;   // node-sub 0..3 within wave
  const int q = lane & 15;     // feature quad: feats 4q..4q+3
  for (int p = 0; p < 8; ++p) {
    int i = p * 16 + wid * 4 + sub;   // local node 0..127
    if (i >= nc) continue;
    int n = n0 + i;
    float wself = __expf(lrelu(sS[n] + sD[n]));
    float dtot = den_s[i] + wself;
    ushort4 h = *(const ushort4*)(H + ((size_t)n << 6) + q * 4);
    float a0 = acc_s[i * 65 + q * 4 + 0];
    float a1 = acc_s[i * 65 + q * 4 + 1];
    float a2 = acc_s[i * 65 + q * 4 + 2];
    float a3 = acc_s[i * 65 + q * 4 + 3];
    float v0 = (a0 + wself * bf2f(h.x)) / dtot + bias[q * 4 + 0];
    float v1 = (a1 + wself * bf2f(h.y)) / dtot + bias[q * 4 + 1];
    float v2 = (a2 + wself * bf2f(h.z)) / dtot + bias[q * 4 + 2];
    float v3 = (a3 + wself * bf2f(h.w)) / dtot + bias[q * 4 + 3];

    if (mode == 0) {
      ushort4 o;
      o.x = f2bf(v0 > 0.f ? v0 : 0.f);
      o.y = f2bf(v1 > 0.f ? v1 : 0.f);
      o.z = f2bf(v2 > 0.f ? v2 : 0.f);
      o.w = f2bf(v3 > 0.f ? v3 : 0.f);
      *(ushort4*)(X1out + (size_t)n * 64 + q * 4) = o;
    } else {
      float sc = v0 * att_c[q * 4 + 0] + v1 * att_c[q * 4 + 1] +
                 v2 * att_c[q * 4 + 2] + v3 * att_c[q * 4 + 3];
      sc += __shfl_xor(sc, 1, 64);
      sc += __shfl_xor(sc, 2, 64);
      sc += __shfl_xor(sc, 4, 64);
      sc += __shfl_xor(sc, 8, 64);
      if (first) {
        *(float4*)(O + (size_t)n * 64 + q * 4) = make_float4(v0, v1, v2, v3);
        if (q == 0) { Mn[n] = sc; Sn[n] = 1.f; }
      } else {
        float M = Mn[n];
        float nM = fmaxf(M, sc);
        float scale = __expf(M - nM);
        float wch = __expf(sc - nM);
        float4 o4 = *(const float4*)(O + (size_t)n * 64 + q * 4);
        float o0 = o4.x * scale + wch * v0;
        float o1 = o4.y * scale + wch * v1;
        float o2 = o4.z * scale + wch * v2;
        float o3 = o4.w * scale + wch * v3;
        float s = Sn[n] * scale + wch;
        if (last) {
          *(float4*)(outF + (size_t)n * 64 + q * 4) =
              make_float4(o0 / s, o1 / s, o2 / s, o3 / s);
        } else {
          *(float4*)(O + (size_t)n * 64 + q * 4) = make_float4(o0, o1, o2, o3);
          if (q == 0) { Mn[n] = nM; Sn[n] = s; }
        }
      }
    }
  }
}

// ---------------- host ----------------

extern "C" void kernel_launch(void* const* d_in, const int* in_sizes, int n_in,
                              void* d_out, int out_size, void* d_ws, size_t ws_size,
                              hipStream_t stream) {
  const float* emb = (const float*)d_in[0];
  const float* W1  = (const float*)d_in[1];
  const float* aS1 = (const float*)d_in[2];
  const float* aD1 = (const float*)d_in[3];
  const float* b1  = (const float*)d_in[4];
  const float* W2  = (const float*)d_in[5];
  const float* aS2 = (const float*)d_in[6];
  const float* aD2 = (const float*)d_in[7];
  const float* b2  = (const float*)d_in[8];
  const float* att = (const float*)d_in[9];
  const int*   EI  = (const int*)d_in[10];
  float* out = (float*)d_out;

  const int gElem = (N_NODES * 64) / 256;    // 25000

  // arena ~49.3 MB; previous rounds proved ws_size >= 56.4 MB
  const size_t NEEDED = 53200000;
  if (ws_size < NEEDED) {
    write_const<<<gElem, 256, 0, stream>>>(out, 1000.0f + (float)(ws_size >> 20));
    return;
  }

  float* ws = (float*)d_ws;
  size_t off = 0;
  float* sS = ws + off; off += 100000;
  float* sD = ws + off; off += 100000;
  float* Mn = ws + off; off += 100000;
  float* Sn = ws + off; off += 100000;
  unsigned short* Hbf  = (unsigned short*)(ws + off); off += 3200000;  // bf16 H
  unsigned short* X1bf = (unsigned short*)(ws + off); off += 3200000;  // bf16 x1
  int* histM     = (int*)(ws + off);      off += (size_t)NSLOT * MLEN + 64;
  int* bsumA     = (int*)(ws + off);      off += NSLOT * 512;
  unsigned* pack = (unsigned*)(ws + off); off += (size_t)NSLOT * PACK_STRIDE;

  const int gGemm = (N_NODES + 127) / 128;   // 782
  // O accumulator for the channel combine lives in d_out (write-only until
  // first channel's layer-1 aggB writes it unconditionally).

  auto build = [&](int base, int nG) {
    histA<<<dim3(NBLK, nG), 256, 0, stream>>>(EI, base, histM);
    scanA1<<<dim3(NBA1, nG), 256, 0, stream>>>(histM, bsumA);
    scanA2<<<nG, 512, 0, stream>>>(bsumA);
    scanA3<<<dim3(NBA1, nG), 256, 0, stream>>>(histM, bsumA);
    scatterA<<<dim3(NBLK, nG), 256, 0, stream>>>(EI, base, histM, pack);
  };

  build(0, 8);                  // graphs 0..7  -> channels 0..3

  for (int c = 0; c < N_CH; ++c) {
    if (c == 4) build(8, 10);   // graphs 8..17 -> channels 4..8 (slots reused)

    for (int layer = 0; layer < 2; ++layer) {
      const int gi = c * 2 + layer;
      const int slot = (gi < 8) ? gi : gi - 8;

      const float* Wf = (layer == 0) ? W1 + (size_t)c * 4096 : W2 + (size_t)c * 4096;
      const float* aS = (layer == 0) ? aS1 + c * 64 : aS2 + c * 64;
      const float* aD = (layer == 0) ? aD1 + c * 64 : aD2 + c * 64;
      const float* bb = (layer == 0) ? b1 + c * 64 : b2 + c * 64;

      if (layer == 0)
        gemm64_f32<<<gGemm, 256, 0, stream>>>(emb, Wf, aS, aD, Hbf, sS, sD, N_NODES);
      else
        gemm64_bf<<<gGemm, 256, 0, stream>>>(X1bf, Wf, aS, aD, Hbf, sS, sD, N_NODES);

      aggB<<<NBUCK, 256, 0, stream>>>(Hbf, sS, sD,
                                      histM + (size_t)slot * MLEN,
                                      pack + (size_t)slot * PACK_STRIDE,
                                      bb, X1bf, att + c * 64,
                                      out, Mn, Sn, out,
                                      layer, (c == 0) ? 1 : 0, (c == N_CH - 1) ? 1 : 0);
    }
  }
}

// Round 6
// 1145.149 us; speedup vs baseline: 4.1820x; 4.1820x over previous
//
#include <hip/hip_runtime.h>
#include <hip/hip_bf16.h>
#include <math.h>

#define N_NODES   100000
#define N_CH      9
#define N_EDG     500000
#define NEG_SLOPE 0.2f
#define NBINS     N_NODES
#define NSLOT     10           // structure slots (batch2 = 10 graphs)
#define PACK_STRIDE 500016     // u32 per graph slot (+16 pad for 4-wide tail reads)

// bucket sort geometry (r4-verified)
#define CHUNK  4096            // edges per block in histA/scatterA
#define NBLK   123             // ceil(500000/4096)
#define NBUCK  391             // buckets of 256 nodes: dst>>8
#define MLEN   (NBUCK * NBLK)  // 48093 matrix entries per graph
#define NBA1   188             // ceil(MLEN/256) scan blocks
#define BCAP   4096            // LDS capacity per bucket (mean 1280, sigma~36)

// ---------------- utility ----------------

__device__ __forceinline__ float bf2f(unsigned short h) {
  return __uint_as_float(((unsigned)h) << 16);
}
// bf16 pair unpack straight from a u32 (lo = elem 2k, hi = elem 2k+1)
__device__ __forceinline__ float bflo(unsigned u) { return __uint_as_float(u << 16); }
__device__ __forceinline__ float bfhi(unsigned u) { return __uint_as_float(u & 0xffff0000u); }
__device__ __forceinline__ unsigned short f2bf(float f) {
  unsigned u = __float_as_uint(f);
  u += 0x7FFFu + ((u >> 16) & 1u);
  return (unsigned short)(u >> 16);
}
__device__ __forceinline__ float lrelu(float x) { return x > 0.f ? x : NEG_SLOPE * x; }
__device__ __forceinline__ int clampi(int x) {
  return x < 0 ? 0 : (x >= N_NODES ? N_NODES - 1 : x);
}

// ---------------- diagnostic: fill output with a constant (f32) ------------
__global__ __launch_bounds__(256) void write_const(float* __restrict__ out, float val) {
  int idx = blockIdx.x * 256 + threadIdx.x;
  out[idx] = val;
}

// ---------------- GEMM + fused attention dots ------------------------------
// H[M,64](bf16) = A[M,64] @ W[64,64](f32); also sS = H.a_src, sD = H.a_dst
// computed from the f32 accumulators (register-resident) via padded-LDS
// reduction.  256 thr, 128 rows/block, 8x4 thread tile.
#define GEMM_BODY(LOAD_A)                                                     \
  __shared__ float Ws[64 * 64];                                               \
  __shared__ float Xs[64 * 132];                                              \
  __shared__ float redS[128 * 17];   /* [row][cg] stride 17: 2-way conflicts */\
  __shared__ float redD[128 * 17];                                            \
  const int tx = threadIdx.x;                                                 \
  const int r0 = blockIdx.x * 128;                                            \
  _Pragma("unroll")                                                           \
  for (int i = 0; i < 16; ++i) Ws[tx + 256 * i] = W[tx + 256 * i];            \
  _Pragma("unroll")                                                           \
  for (int it = 0; it < 8; ++it) {                                            \
    int f = tx + 256 * it;                                                    \
    int r = f >> 4;                                                           \
    int k0 = (f & 15) << 2;                                                   \
    float4 v = make_float4(0.f, 0.f, 0.f, 0.f);                               \
    if (r0 + r < M) { LOAD_A }                                                \
    Xs[(k0 + 0) * 132 + r] = v.x;                                             \
    Xs[(k0 + 1) * 132 + r] = v.y;                                             \
    Xs[(k0 + 2) * 132 + r] = v.z;                                             \
    Xs[(k0 + 3) * 132 + r] = v.w;                                             \
  }                                                                           \
  __syncthreads();                                                            \
  const int cg = tx & 15, rg = tx >> 4;                                       \
  float acc[8][4];                                                            \
  _Pragma("unroll")                                                           \
  for (int i = 0; i < 8; ++i)                                                 \
    _Pragma("unroll")                                                         \
    for (int j = 0; j < 4; ++j) acc[i][j] = 0.f;                              \
  _Pragma("unroll 4")                                                         \
  for (int k = 0; k < 64; ++k) {                                              \
    float4 w4 = *(const float4*)(Ws + k * 64 + cg * 4);                       \
    float4 x0 = *(const float4*)(Xs + k * 132 + rg * 8);                      \
    float4 x1 = *(const float4*)(Xs + k * 132 + rg * 8 + 4);                  \
    float xr[8] = {x0.x, x0.y, x0.z, x0.w, x1.x, x1.y, x1.z, x1.w};           \
    float wr[4] = {w4.x, w4.y, w4.z, w4.w};                                   \
    _Pragma("unroll")                                                         \
    for (int i = 0; i < 8; ++i)                                               \
      _Pragma("unroll")                                                       \
      for (int j = 0; j < 4; ++j) acc[i][j] += xr[i] * wr[j];                 \
  }                                                                           \
  float4 s4 = *(const float4*)(a_src + cg * 4);                               \
  float4 d4 = *(const float4*)(a_dst + cg * 4);                               \
  _Pragma("unroll")                                                           \
  for (int i = 0; i < 8; ++i) {                                               \
    int row = rg * 8 + i;                                                     \
    redS[row * 17 + cg] =                                                     \
        acc[i][0] * s4.x + acc[i][1] * s4.y + acc[i][2] * s4.z + acc[i][3] * s4.w; \
    redD[row * 17 + cg] =                                                     \
        acc[i][0] * d4.x + acc[i][1] * d4.y + acc[i][2] * d4.z + acc[i][3] * d4.w; \
    int r = r0 + row;                                                         \
    if (r < M) {                                                              \
      ushort4 o;                                                              \
      o.x = f2bf(acc[i][0]); o.y = f2bf(acc[i][1]);                           \
      o.z = f2bf(acc[i][2]); o.w = f2bf(acc[i][3]);                           \
      *(ushort4*)(Hout + (size_t)r * 64 + cg * 4) = o;                        \
    }                                                                         \
  }                                                                           \
  __syncthreads();                                                            \
  if (tx < 128) {                                                             \
    float s = 0.f;                                                            \
    _Pragma("unroll")                                                         \
    for (int c2 = 0; c2 < 16; ++c2) s += redS[tx * 17 + c2];                  \
    if (r0 + tx < M) sS[r0 + tx] = s;                                         \
  } else {                                                                    \
    int row = tx - 128;                                                       \
    float s = 0.f;                                                            \
    _Pragma("unroll")                                                         \
    for (int c2 = 0; c2 < 16; ++c2) s += redD[row * 17 + c2];                 \
    if (r0 + row < M) sD[r0 + row] = s;                                       \
  }

__global__ __launch_bounds__(256) void gemm64_f32(const float* __restrict__ A,
                                                  const float* __restrict__ W,
                                                  const float* __restrict__ a_src,
                                                  const float* __restrict__ a_dst,
                                                  unsigned short* __restrict__ Hout,
                                                  float* __restrict__ sS,
                                                  float* __restrict__ sD, int M) {
  GEMM_BODY(v = *(const float4*)(A + (size_t)(r0 + r) * 64 + k0);)
}

__global__ __launch_bounds__(256) void gemm64_bf(const unsigned short* __restrict__ A,
                                                 const float* __restrict__ W,
                                                 const float* __restrict__ a_src,
                                                 const float* __restrict__ a_dst,
                                                 unsigned short* __restrict__ Hout,
                                                 float* __restrict__ sS,
                                                 float* __restrict__ sD, int M) {
  GEMM_BODY(ushort4 h = *(const ushort4*)(A + (size_t)(r0 + r) * 64 + k0);
            v.x = bf2f(h.x); v.y = bf2f(h.y); v.z = bf2f(h.z); v.w = bf2f(h.w);)
}

// ---------------- batched CSR build: atomic-free two-level bucket sort -----
// (r4-verified structure, restored verbatim after r5's aggB regression)

__global__ __launch_bounds__(256) void histA(const int* __restrict__ EI, int base,
                                             int* __restrict__ histM) {
  const int g = blockIdx.y;
  const int* dst = EI + ((size_t)(base + g) * 2 + 1) * N_EDG;
  __shared__ int h[NBUCK];
  for (int i = threadIdx.x; i < NBUCK; i += 256) h[i] = 0;
  __syncthreads();
  const int e0 = blockIdx.x * CHUNK;
#pragma unroll
  for (int k = 0; k < CHUNK; k += 256) {
    int i = e0 + k + threadIdx.x;
    if (i < N_EDG) atomicAdd(&h[clampi(dst[i]) >> 8], 1);
  }
  __syncthreads();
  for (int i = threadIdx.x; i < NBUCK; i += 256)
    histM[(size_t)g * MLEN + i * NBLK + blockIdx.x] = h[i];
}

__global__ __launch_bounds__(256) void scanA1(int* __restrict__ data,
                                              int* __restrict__ bsum) {
  const int g = blockIdx.y;
  __shared__ int sh[256];
  int i = blockIdx.x * 256 + threadIdx.x;
  int x = (i < MLEN) ? data[(size_t)g * MLEN + i] : 0;
  sh[threadIdx.x] = x;
  __syncthreads();
  for (int off = 1; off < 256; off <<= 1) {
    int t = (threadIdx.x >= off) ? sh[threadIdx.x - off] : 0;
    __syncthreads();
    sh[threadIdx.x] += t;
    __syncthreads();
  }
  if (i < MLEN) data[(size_t)g * MLEN + i] = sh[threadIdx.x] - x;  // exclusive
  if (threadIdx.x == 255) bsum[g * 512 + blockIdx.x] = sh[255];
}

__global__ __launch_bounds__(512) void scanA2(int* __restrict__ bsum) {
  const int g = blockIdx.x;
  __shared__ int sh[512];
  int x = (threadIdx.x < NBA1) ? bsum[g * 512 + threadIdx.x] : 0;
  sh[threadIdx.x] = x;
  __syncthreads();
  for (int off = 1; off < 512; off <<= 1) {
    int t = (threadIdx.x >= off) ? sh[threadIdx.x - off] : 0;
    __syncthreads();
    sh[threadIdx.x] += t;
    __syncthreads();
  }
  if (threadIdx.x < NBA1) bsum[g * 512 + threadIdx.x] = sh[threadIdx.x] - x;  // exclusive
}

__global__ void scanA3(int* __restrict__ data, const int* __restrict__ bsum) {
  const int g = blockIdx.y;
  int i = blockIdx.x * 256 + threadIdx.x;
  if (i < MLEN) data[(size_t)g * MLEN + i] += bsum[g * 512 + blockIdx.x];
}

// block-local counting sort by coarse bucket + coalesced sequential writeout.
__global__ __launch_bounds__(256) void scatterA(const int* __restrict__ EI, int base,
                                                const int* __restrict__ histM,
                                                unsigned* __restrict__ pack) {
  const int g = blockIdx.y;
  const int* srcp = EI + ((size_t)(base + g) * 2 + 0) * N_EDG;
  const int* dstp = EI + ((size_t)(base + g) * 2 + 1) * N_EDG;
  __shared__ unsigned ed[CHUNK];          // 16 KB: bucket-grouped entries
  __shared__ unsigned short bkt[CHUNK];   // 8 KB: bucket id per slot
  __shared__ int lcnt[NBUCK];
  __shared__ int ebase[NBUCK];
  __shared__ int gbase[NBUCK];
  __shared__ int sc[512];
  const int t = threadIdx.x;
  const int e0 = blockIdx.x * CHUNK;
  const int nE = (N_EDG - e0 < CHUNK) ? (N_EDG - e0) : CHUNK;

  for (int i = t; i < NBUCK; i += 256) {
    lcnt[i] = 0;
    gbase[i] = histM[(size_t)g * MLEN + i * NBLK + blockIdx.x];
  }
  __syncthreads();
  // pass 1: local histogram (reads dst; stays hot in L1/L2 for pass 2)
  for (int k = t; k < nE; k += 256)
    atomicAdd(&lcnt[clampi(dstp[e0 + k]) >> 8], 1);
  __syncthreads();
  // block-wide inclusive scan of 512-padded lcnt (each thread owns 2 slots)
  int v0 = (t < NBUCK) ? lcnt[t] : 0;
  int v1 = (t + 256 < NBUCK) ? lcnt[t + 256] : 0;
  sc[t] = v0; sc[t + 256] = v1;
  __syncthreads();
  for (int off = 1; off < 512; off <<= 1) {
    int a0 = (t >= off) ? sc[t - off] : 0;
    int a1 = (t + 256 >= off) ? sc[t + 256 - off] : 0;
    __syncthreads();
    sc[t] += a0; sc[t + 256] += a1;
    __syncthreads();
  }
  if (t < NBUCK)       { ebase[t] = sc[t] - v0;             lcnt[t] = 0; }
  if (t + 256 < NBUCK) { ebase[t + 256] = sc[t + 256] - v1; lcnt[t + 256] = 0; }
  __syncthreads();
  // pass 2: scatter into LDS, bucket-grouped (rank via LDS atomics)
  for (int k = t; k < nE; k += 256) {
    int d = clampi(dstp[e0 + k]);
    int s = clampi(srcp[e0 + k]);
    int b = d >> 8;
    int slot = ebase[b] + atomicAdd(&lcnt[b], 1);
    ed[slot] = ((unsigned)s << 8) | (unsigned)(d & 255);
    bkt[slot] = (unsigned short)b;
  }
  __syncthreads();
  // pass 3: sequential write-out -> bucket-runs leave as consecutive lanes
  unsigned* pk = pack + (size_t)g * PACK_STRIDE;
  for (int i = t; i < nE; i += 256) {
    int b = bkt[i];
    pk[gbase[b] + (i - ebase[b])] = ed[i];
  }
}

__global__ __launch_bounds__(256) void sortB(const int* __restrict__ histM,
                                             unsigned* __restrict__ pack,
                                             int* __restrict__ rp) {
  const int g = blockIdx.y;
  const int b = blockIdx.x;   // bucket 0..390
  __shared__ unsigned ed[BCAP];
  __shared__ unsigned ed2[BCAP];
  __shared__ int cnt[256];
  __shared__ int sh[256];
  const int t = threadIdx.x;
  const int beg = histM[(size_t)g * MLEN + b * NBLK];
  const int end = (b + 1 < NBUCK) ? histM[(size_t)g * MLEN + (b + 1) * NBLK] : N_EDG;
  int m = end - beg;
  if (m > BCAP) m = BCAP;   // defensive: statistically impossible (78 sigma)
  unsigned* pk = pack + (size_t)g * PACK_STRIDE;

  cnt[t] = 0;
  __syncthreads();
  for (int i = t; i < m; i += 256) {
    unsigned w = pk[beg + i];
    ed[i] = w;
    atomicAdd(&cnt[w & 255u], 1);
  }
  __syncthreads();
  // block-wide Hillis-Steele inclusive scan of cnt -> sh
  int x = cnt[t];
  sh[t] = x;
  __syncthreads();
  for (int off = 1; off < 256; off <<= 1) {
    int tt = (t >= off) ? sh[t - off] : 0;
    __syncthreads();
    sh[t] += tt;
    __syncthreads();
  }
  // rp end-offsets for this bucket's nodes (global edge indexing)
  int n = b * 256 + t;
  if (n < N_NODES) rp[(size_t)g * NBINS + n] = beg + sh[t];
  // cursor = exclusive base
  cnt[t] = sh[t] - x;
  __syncthreads();
  // counting-sort scatter within LDS (order within a node is irrelevant)
  for (int i = t; i < m; i += 256) {
    unsigned w = ed[i];
    int pos = atomicAdd(&cnt[w & 255u], 1);
    ed2[pos] = w >> 8;                    // keep src only
  }
  __syncthreads();
  // in-place, fully coalesced write-back of dst-sorted src list
  for (int i = t; i < m; i += 256) pk[beg + i] = ed2[i];
}

// ---------------- per-node GAT aggregation (16 lanes per node) -------------
// Lane f = tx&15 permanently owns features 4f..4f+3: the feature dimension
// never crosses lanes -> NO reduction shuffles (r4's ~35-shuffle epilogue
// was ~half the wave lifetime).  Each wave = 4 nodes; 4 edges unrolled per
// iter keep >=4 independent gather chains in flight.  pack[j]/sS[s] are
// 16-lane broadcast loads; H gather = 16 lanes x 8B = 128B/row.
// den is lane-redundant (no reduce).  mode 0: X1=bf16(relu(v)); mode 1:
// online channel combine (O,Mn,Sn), last channel writes final f32 out.
__global__ __launch_bounds__(256) void aggregate(const unsigned short* __restrict__ H,
                                                 const float* __restrict__ sS,
                                                 const float* __restrict__ sD,
                                                 const int* __restrict__ rp,  // end offsets
                                                 const unsigned* __restrict__ pack,
                                                 const float* __restrict__ bias,
                                                 unsigned short* __restrict__ X1out,
                                                 const float* __restrict__ att_c,
                                                 float* __restrict__ O,
                                                 float* __restrict__ Mn,
                                                 float* __restrict__ Sn,
                                                 float* __restrict__ outF,
                                                 int mode, int first, int last) {
  const int n = blockIdx.x * 16 + (threadIdx.x >> 4);
  const int f = threadIdx.x & 15;       // feature quad: feats 4f..4f+3
  const int beg = (n == 0) ? 0 : rp[n - 1];
  const int end = rp[n];
  const float sDn = sD[n];
  const float wself = __expf(lrelu(sS[n] + sDn));

  // self loop
  uint2 hs = *(const uint2*)(H + ((size_t)n << 6) + (f << 2));
  float a0 = wself * bflo(hs.x);
  float a1 = wself * bfhi(hs.x);
  float a2 = wself * bflo(hs.y);
  float a3 = wself * bfhi(hs.y);
  float den = wself;

  for (int j = beg; j < end; j += 4) {
    unsigned p0 = pack[j];          // padded slot: tail reads safe
    unsigned p1 = pack[j + 1];
    unsigned p2 = pack[j + 2];
    unsigned p3 = pack[j + 3];
    int s0 = (j + 0 < end) ? (int)p0 : n;
    int s1 = (j + 1 < end) ? (int)p1 : n;
    int s2 = (j + 2 < end) ? (int)p2 : n;
    int s3 = (j + 3 < end) ? (int)p3 : n;
    float w0 = (j + 0 < end) ? __expf(lrelu(sS[s0] + sDn)) : 0.f;
    float w1 = (j + 1 < end) ? __expf(lrelu(sS[s1] + sDn)) : 0.f;
    float w2 = (j + 2 < end) ? __expf(lrelu(sS[s2] + sDn)) : 0.f;
    float w3 = (j + 3 < end) ? __expf(lrelu(sS[s3] + sDn)) : 0.f;
    uint2 h0 = *(const uint2*)(H + ((size_t)s0 << 6) + (f << 2));
    uint2 h1 = *(const uint2*)(H + ((size_t)s1 << 6) + (f << 2));
    uint2 h2 = *(const uint2*)(H + ((size_t)s2 << 6) + (f << 2));
    uint2 h3 = *(const uint2*)(H + ((size_t)s3 << 6) + (f << 2));
    den += w0 + w1 + w2 + w3;
    a0 += w0 * bflo(h0.x) + w1 * bflo(h1.x) + w2 * bflo(h2.x) + w3 * bflo(h3.x);
    a1 += w0 * bfhi(h0.x) + w1 * bfhi(h1.x) + w2 * bfhi(h2.x) + w3 * bfhi(h3.x);
    a2 += w0 * bflo(h0.y) + w1 * bflo(h1.y) + w2 * bflo(h2.y) + w3 * bflo(h3.y);
    a3 += w0 * bfhi(h0.y) + w1 * bfhi(h1.y) + w2 * bfhi(h2.y) + w3 * bfhi(h3.y);
  }

  float v0 = a0 / den + bias[f * 4 + 0];
  float v1 = a1 / den + bias[f * 4 + 1];
  float v2 = a2 / den + bias[f * 4 + 2];
  float v3 = a3 / den + bias[f * 4 + 3];

  if (mode == 0) {
    ushort4 o;
    o.x = f2bf(v0 > 0.f ? v0 : 0.f);
    o.y = f2bf(v1 > 0.f ? v1 : 0.f);
    o.z = f2bf(v2 > 0.f ? v2 : 0.f);
    o.w = f2bf(v3 > 0.f ? v3 : 0.f);
    *(ushort4*)(X1out + (size_t)n * 64 + f * 4) = o;
  } else {
    float sc = v0 * att_c[f * 4 + 0] + v1 * att_c[f * 4 + 1] +
               v2 * att_c[f * 4 + 2] + v3 * att_c[f * 4 + 3];
    sc += __shfl_xor(sc, 1, 16);
    sc += __shfl_xor(sc, 2, 16);
    sc += __shfl_xor(sc, 4, 16);
    sc += __shfl_xor(sc, 8, 16);
    if (first) {
      *(float4*)(O + (size_t)n * 64 + f * 4) = make_float4(v0, v1, v2, v3);
      if (f == 0) { Mn[n] = sc; Sn[n] = 1.f; }
    } else {
      float M = Mn[n];
      float nM = fmaxf(M, sc);
      float scale = __expf(M - nM);
      float wch = __expf(sc - nM);
      float4 o4 = *(const float4*)(O + (size_t)n * 64 + f * 4);
      float o0 = o4.x * scale + wch * v0;
      float o1 = o4.y * scale + wch * v1;
      float o2 = o4.z * scale + wch * v2;
      float o3 = o4.w * scale + wch * v3;
      float s = Sn[n] * scale + wch;
      if (last) {
        *(float4*)(outF + (size_t)n * 64 + f * 4) =
            make_float4(o0 / s, o1 / s, o2 / s, o3 / s);
      } else {
        *(float4*)(O + (size_t)n * 64 + f * 4) = make_float4(o0, o1, o2, o3);
        if (f == 0) { Mn[n] = nM; Sn[n] = s; }
      }
    }
  }
}

// ---------------- host ----------------

extern "C" void kernel_launch(void* const* d_in, const int* in_sizes, int n_in,
                              void* d_out, int out_size, void* d_ws, size_t ws_size,
                              hipStream_t stream) {
  const float* emb = (const float*)d_in[0];
  const float* W1  = (const float*)d_in[1];
  const float* aS1 = (const float*)d_in[2];
  const float* aD1 = (const float*)d_in[3];
  const float* b1  = (const float*)d_in[4];
  const float* W2  = (const float*)d_in[5];
  const float* aS2 = (const float*)d_in[6];
  const float* aD2 = (const float*)d_in[7];
  const float* b2  = (const float*)d_in[8];
  const float* att = (const float*)d_in[9];
  const int*   EI  = (const int*)d_in[10];
  float* out = (float*)d_out;

  const int gElem = (N_NODES * 64) / 256;    // 25000

  // arena ~53.15 MB; previous rounds proved ws_size >= 56.4 MB
  const size_t NEEDED = 53200000;
  if (ws_size < NEEDED) {
    write_const<<<gElem, 256, 0, stream>>>(out, 1000.0f + (float)(ws_size >> 20));
    return;
  }

  float* ws = (float*)d_ws;
  size_t off = 0;
  float* sS = ws + off; off += 100000;
  float* sD = ws + off; off += 100000;
  float* Mn = ws + off; off += 100000;
  float* Sn = ws + off; off += 100000;
  unsigned short* Hbf  = (unsigned short*)(ws + off); off += 3200000;  // bf16 H
  unsigned short* X1bf = (unsigned short*)(ws + off); off += 3200000;  // bf16 x1
  int* histM     = (int*)(ws + off);      off += (size_t)NSLOT * MLEN + 64;
  int* bsumA     = (int*)(ws + off);      off += NSLOT * 512;
  int* rp        = (int*)(ws + off);      off += (size_t)NSLOT * NBINS;
  unsigned* pack = (unsigned*)(ws + off); off += (size_t)NSLOT * PACK_STRIDE;

  const int gGemm = (N_NODES + 127) / 128;   // 782
  const int gRow  = N_NODES / 16;            // 6250
  // O accumulator for the channel combine lives in d_out (write-only until
  // first channel's layer-1 aggregate writes it unconditionally).

  auto build = [&](int base, int nG) {
    histA<<<dim3(NBLK, nG), 256, 0, stream>>>(EI, base, histM);
    scanA1<<<dim3(NBA1, nG), 256, 0, stream>>>(histM, bsumA);
    scanA2<<<nG, 512, 0, stream>>>(bsumA);
    scanA3<<<dim3(NBA1, nG), 256, 0, stream>>>(histM, bsumA);
    scatterA<<<dim3(NBLK, nG), 256, 0, stream>>>(EI, base, histM, pack);
    sortB<<<dim3(NBUCK, nG), 256, 0, stream>>>(histM, pack, rp);
  };

  build(0, 8);                  // graphs 0..7  -> channels 0..3

  for (int c = 0; c < N_CH; ++c) {
    if (c == 4) build(8, 10);   // graphs 8..17 -> channels 4..8 (slots reused)

    for (int layer = 0; layer < 2; ++layer) {
      const int gi = c * 2 + layer;
      const int slot = (gi < 8) ? gi : gi - 8;

      const float* Wf = (layer == 0) ? W1 + (size_t)c * 4096 : W2 + (size_t)c * 4096;
      const float* aS = (layer == 0) ? aS1 + c * 64 : aS2 + c * 64;
      const float* aD = (layer == 0) ? aD1 + c * 64 : aD2 + c * 64;
      const float* bb = (layer == 0) ? b1 + c * 64 : b2 + c * 64;

      if (layer == 0)
        gemm64_f32<<<gGemm, 256, 0, stream>>>(emb, Wf, aS, aD, Hbf, sS, sD, N_NODES);
      else
        gemm64_bf<<<gGemm, 256, 0, stream>>>(X1bf, Wf, aS, aD, Hbf, sS, sD, N_NODES);

      aggregate<<<gRow, 256, 0, stream>>>(Hbf, sS, sD,
                                          rp + (size_t)slot * NBINS,
                                          pack + (size_t)slot * PACK_STRIDE,
                                          bb, X1bf, att + c * 64,
                                          out, Mn, Sn, out,
                                          layer, (c == 0) ? 1 : 0, (c == N_CH - 1) ? 1 : 0);
    }
  }
}